// Round 1
// baseline (466.690 us; speedup 1.0000x reference)
//
#include <hip/hip_runtime.h>
#include <hip/hip_bf16.h>

#define D 256
#define DH 128
#define NB 8   // nodes per wave in score kernel

// ---------------------------------------------------------------------------
// Detect whether edge_index is int64 (high words all zero) or int32.
// flag must be pre-zeroed. After this kernel: flag==0  -> int64, else int32.
__global__ __launch_bounds__(256) void detect_kernel(const int* __restrict__ ei,
                                                     int* __restrict__ flag, int E) {
    int tid = threadIdx.x;
    int limit = min(E, 4096);
    int v = 0;
    for (int i = tid; i < limit; i += 256) v |= ei[2 * i + 1];
#pragma unroll
    for (int off = 32; off > 0; off >>= 1) v |= __shfl_down(v, off, 64);
    if ((tid & 63) == 0) atomicOr(flag, v);
}

__device__ __forceinline__ int eload(const void* p, long long i, int is64) {
    if (is64) return (int)((const long long*)p)[i];
    return ((const int*)p)[i];
}

// ---------------------------------------------------------------------------
// Per-node attention score: s[n] = sigmoid( relu(x[n]@W1 + b1) @ W2 + b2 )
// One wave handles NB=8 nodes; lane j computes hidden cols j and j+64.
__global__ __launch_bounds__(256) void score_kernel(const float* __restrict__ x,
                                                    const float* __restrict__ W1,
                                                    const float* __restrict__ b1,
                                                    const float* __restrict__ W2,
                                                    const float* __restrict__ b2,
                                                    float* __restrict__ s, int N) {
    __shared__ __align__(16) float xs[4][NB][D];   // 32 KB
    int lane = threadIdx.x & 63;
    int wid  = threadIdx.x >> 6;
    int base = (blockIdx.x * 4 + wid) * NB;

    // stage x rows for this wave's 8 nodes (float4 per lane per row)
#pragma unroll
    for (int m = 0; m < NB; ++m) {
        int n = base + m;
        float4 v = make_float4(0.f, 0.f, 0.f, 0.f);
        if (n < N) v = ((const float4*)x)[(size_t)n * 64 + lane];
        ((float4*)&xs[wid][m][0])[lane] = v;
    }
    __syncthreads();

    float h0[NB], h1[NB];
#pragma unroll
    for (int m = 0; m < NB; ++m) { h0[m] = 0.f; h1[m] = 0.f; }

#pragma unroll 4
    for (int k = 0; k < D; ++k) {
        float w1a = W1[k * DH + lane];
        float w1b = W1[k * DH + 64 + lane];
#pragma unroll
        for (int m = 0; m < NB; ++m) {
            float xv = xs[wid][m][k];
            h0[m] = fmaf(xv, w1a, h0[m]);
            h1[m] = fmaf(xv, w1b, h1[m]);
        }
    }

    float b1a = b1[lane], b1b = b1[lane + 64];
    float w2a = W2[lane], w2b = W2[lane + 64];
    float b2v = b2[0];
#pragma unroll
    for (int m = 0; m < NB; ++m) {
        float za = fmaxf(h0[m] + b1a, 0.f) * w2a + fmaxf(h1[m] + b1b, 0.f) * w2b;
#pragma unroll
        for (int off = 32; off > 0; off >>= 1) za += __shfl_down(za, off, 64);
        if (lane == 0) {
            int n = base + m;
            if (n < N) s[n] = 1.f / (1.f + __expf(-(za + b2v)));
        }
    }
}

// ---------------------------------------------------------------------------
__global__ __launch_bounds__(256) void hist_kernel(const void* __restrict__ ep,
                                                   const int* __restrict__ flag,
                                                   int* __restrict__ cnt, int E) {
    int is64 = (*flag == 0);
    int e = blockIdx.x * blockDim.x + threadIdx.x;
    if (e < E) atomicAdd(&cnt[eload(ep, e, is64)], 1);
}

// single-block exclusive scan over cnt[0..N) -> offs[0..N], cursor copy
__global__ __launch_bounds__(1024) void scan_kernel(const int* __restrict__ cnt,
                                                    int* __restrict__ offs,
                                                    int* __restrict__ cursor, int N) {
    __shared__ int tmp[1024];
    __shared__ int carry_s;
    int tid = threadIdx.x;
    if (tid == 0) carry_s = 0;
    __syncthreads();
    for (int base = 0; base < N; base += 1024) {
        int v = (base + tid < N) ? cnt[base + tid] : 0;
        tmp[tid] = v;
        __syncthreads();
        for (int off = 1; off < 1024; off <<= 1) {
            int t = (tid >= off) ? tmp[tid - off] : 0;
            __syncthreads();
            tmp[tid] += t;
            __syncthreads();
        }
        int inc = tmp[tid];
        int total = tmp[1023];
        int cb = carry_s;
        __syncthreads();
        if (base + tid < N) {
            int e = cb + inc - v;
            offs[base + tid] = e;
            cursor[base + tid] = e;
        }
        if (tid == 0) carry_s = cb + total;
        __syncthreads();
    }
    if (tid == 0) offs[N] = carry_s;
}

__global__ __launch_bounds__(256) void scatter_kernel(const void* __restrict__ ep,
                                                      const int* __restrict__ flag,
                                                      int* __restrict__ cursor,
                                                      int* __restrict__ cols, int E) {
    int is64 = (*flag == 0);
    int e = blockIdx.x * blockDim.x + threadIdx.x;
    if (e < E) {
        int r = eload(ep, e, is64);
        int c = eload(ep, (long long)E + e, is64);
        int p = atomicAdd(&cursor[r], 1);
        cols[p] = c;
    }
}

// ---------------------------------------------------------------------------
// One wave per destination node; lane l owns feature dims 4l..4l+3.
__global__ __launch_bounds__(256) void agg_kernel(const float4* __restrict__ x4,
                                                  const float* __restrict__ s,
                                                  const int* __restrict__ offs,
                                                  const int* __restrict__ cols,
                                                  float4* __restrict__ out4, int N) {
    int lane = threadIdx.x & 63;
    int node = blockIdx.x * 4 + (threadIdx.x >> 6);
    if (node >= N) return;
    int beg = offs[node], end = offs[node + 1];
    float4 acc = make_float4(0.f, 0.f, 0.f, 0.f);
    float den = 0.f;
    for (int k = beg; k < end; ++k) {
        int c = cols[k];
        float sc = s[c];
        float4 xv = x4[(size_t)c * 64 + lane];
        acc.x = fmaf(xv.x, sc, acc.x);
        acc.y = fmaf(xv.y, sc, acc.y);
        acc.z = fmaf(xv.z, sc, acc.z);
        acc.w = fmaf(xv.w, sc, acc.w);
        den += sc;
    }
    float4 o = make_float4(0.f, 0.f, 0.f, 0.f);
    if (end > beg) {
        float inv = 1.f / den;
        o.x = acc.x * inv; o.y = acc.y * inv; o.z = acc.z * inv; o.w = acc.w * inv;
    }
    out4[(size_t)node * 64 + lane] = o;
}

// ---------------------------------------------------------------------------
extern "C" void kernel_launch(void* const* d_in, const int* in_sizes, int n_in,
                              void* d_out, int out_size, void* d_ws, size_t ws_size,
                              hipStream_t stream) {
    const float* x  = (const float*)d_in[0];
    const void*  ei = d_in[1];
    const float* W1 = (const float*)d_in[2];
    const float* b1 = (const float*)d_in[3];
    const float* W2 = (const float*)d_in[4];
    const float* b2 = (const float*)d_in[5];
    int N = in_sizes[0] / D;
    int E = in_sizes[1] / 2;

    char* ws = (char*)d_ws;
    size_t o0 = 0;                                   // flag (16 B slot)
    size_t o1 = 16;                                  // cnt    : N ints
    size_t o2 = (o1 + (size_t)N * 4 + 15) & ~15ull;  // offs   : N+1 ints
    size_t o3 = (o2 + (size_t)(N + 1) * 4 + 15) & ~15ull; // cursor : N ints
    size_t o4 = (o3 + (size_t)N * 4 + 15) & ~15ull;  // s      : N floats
    size_t o5 = (o4 + (size_t)N * 4 + 15) & ~15ull;  // cols   : E ints
    int*   flag   = (int*)(ws + o0);
    int*   cnt    = (int*)(ws + o1);
    int*   offs   = (int*)(ws + o2);
    int*   cursor = (int*)(ws + o3);
    float* s      = (float*)(ws + o4);
    int*   cols   = (int*)(ws + o5);

    // zero flag + histogram
    hipMemsetAsync(ws, 0, o1 + (size_t)N * 4, stream);

    detect_kernel<<<1, 256, 0, stream>>>((const int*)ei, flag, E);
    score_kernel<<<(N + 4 * NB - 1) / (4 * NB), 256, 0, stream>>>(x, W1, b1, W2, b2, s, N);
    hist_kernel<<<(E + 255) / 256, 256, 0, stream>>>(ei, flag, cnt, E);
    scan_kernel<<<1, 1024, 0, stream>>>(cnt, offs, cursor, N);
    scatter_kernel<<<(E + 255) / 256, 256, 0, stream>>>(ei, flag, cursor, cols, E);
    agg_kernel<<<(N + 3) / 4, 256, 0, stream>>>((const float4*)x, s, offs, cols,
                                                (float4*)d_out, N);
}

// Round 2
// 426.491 us; speedup vs baseline: 1.0943x; 1.0943x over previous
//
#include <hip/hip_runtime.h>
#include <hip/hip_bf16.h>

#define D 256
#define DH 128
#define NB 8   // nodes per wave in score kernel

// ---------------------------------------------------------------------------
// Detect whether edge_index is int64 (high words all zero) or int32.
// flag must be pre-zeroed. After this kernel: flag==0 -> int64, else int32.
__global__ __launch_bounds__(256) void detect_kernel(const int* __restrict__ ei,
                                                     int* __restrict__ flag, int E) {
    int tid = threadIdx.x;
    int limit = min(E, 4096);
    int v = 0;
    for (int i = tid; i < limit; i += 256) v |= ei[2 * i + 1];
#pragma unroll
    for (int off = 32; off > 0; off >>= 1) v |= __shfl_down(v, off, 64);
    if ((tid & 63) == 0) atomicOr(flag, v);
}

__device__ __forceinline__ int eload(const void* p, long long i, int is64) {
    if (is64) return (int)((const long long*)p)[i];
    return ((const int*)p)[i];
}

// ---------------------------------------------------------------------------
// x (fp32) -> bf16 with round-to-nearest-even. n4 = count of float4 elements.
__device__ __forceinline__ unsigned pack_bf16(unsigned a, unsigned b) {
    unsigned ra = (a + 0x7fffu + ((a >> 16) & 1u)) >> 16;
    unsigned rb = (b + 0x7fffu + ((b >> 16) & 1u)) & 0xffff0000u;
    return ra | rb;
}

__global__ __launch_bounds__(256) void cast_kernel(const uint4* __restrict__ xi,
                                                   uint2* __restrict__ xb, int n4) {
    int i = blockIdx.x * blockDim.x + threadIdx.x;
    if (i < n4) {
        uint4 f = xi[i];
        uint2 o;
        o.x = pack_bf16(f.x, f.y);
        o.y = pack_bf16(f.z, f.w);
        xb[i] = o;
    }
}

// ---------------------------------------------------------------------------
// Per-node attention score: s[n] = sigmoid( relu(x[n]@W1 + b1) @ W2 + b2 )
// One wave handles NB=8 nodes; lane j computes hidden cols j and j+64.
__global__ __launch_bounds__(256) void score_kernel(const float* __restrict__ x,
                                                    const float* __restrict__ W1,
                                                    const float* __restrict__ b1,
                                                    const float* __restrict__ W2,
                                                    const float* __restrict__ b2,
                                                    float* __restrict__ s, int N) {
    __shared__ __align__(16) float xs[4][NB][D];   // 32 KB
    int lane = threadIdx.x & 63;
    int wid  = threadIdx.x >> 6;
    int base = (blockIdx.x * 4 + wid) * NB;

#pragma unroll
    for (int m = 0; m < NB; ++m) {
        int n = base + m;
        float4 v = make_float4(0.f, 0.f, 0.f, 0.f);
        if (n < N) v = ((const float4*)x)[(size_t)n * 64 + lane];
        ((float4*)&xs[wid][m][0])[lane] = v;
    }
    __syncthreads();

    float h0[NB], h1[NB];
#pragma unroll
    for (int m = 0; m < NB; ++m) { h0[m] = 0.f; h1[m] = 0.f; }

#pragma unroll 4
    for (int k = 0; k < D; ++k) {
        float w1a = W1[k * DH + lane];
        float w1b = W1[k * DH + 64 + lane];
#pragma unroll
        for (int m = 0; m < NB; ++m) {
            float xv = xs[wid][m][k];
            h0[m] = fmaf(xv, w1a, h0[m]);
            h1[m] = fmaf(xv, w1b, h1[m]);
        }
    }

    float b1a = b1[lane], b1b = b1[lane + 64];
    float w2a = W2[lane], w2b = W2[lane + 64];
    float b2v = b2[0];
#pragma unroll
    for (int m = 0; m < NB; ++m) {
        float za = fmaxf(h0[m] + b1a, 0.f) * w2a + fmaxf(h1[m] + b1b, 0.f) * w2b;
#pragma unroll
        for (int off = 32; off > 0; off >>= 1) za += __shfl_down(za, off, 64);
        if (lane == 0) {
            int n = base + m;
            if (n < N) s[n] = 1.f / (1.f + __expf(-(za + b2v)));
        }
    }
}

// ---------------------------------------------------------------------------
__global__ __launch_bounds__(256) void hist_kernel(const void* __restrict__ ep,
                                                   const int* __restrict__ flag,
                                                   int* __restrict__ cnt, int E) {
    int is64 = (*flag == 0);
    int e = blockIdx.x * blockDim.x + threadIdx.x;
    if (e < E) atomicAdd(&cnt[eload(ep, e, is64)], 1);
}

// ---------------------------------------------------------------------------
// Chunked single-block exclusive scan: thread t serially sums a chunk, one
// 10-step LDS scan of the 1024 partials, then serial write-back.
__global__ __launch_bounds__(1024) void scan_kernel(const int* __restrict__ cnt,
                                                    int* __restrict__ offs,
                                                    int* __restrict__ cursor, int N) {
    __shared__ int tmp[1024];
    int tid = threadIdx.x;
    int C = (N + 1023) >> 10;
    int start = tid * C;
    int end = min(start + C, N);

    int sum = 0;
    for (int i = start; i < end; ++i) sum += cnt[i];

    tmp[tid] = sum;
    __syncthreads();
    for (int off = 1; off < 1024; off <<= 1) {
        int t = (tid >= off) ? tmp[tid - off] : 0;
        __syncthreads();
        tmp[tid] += t;
        __syncthreads();
    }
    int run = tmp[tid] - sum;   // exclusive prefix of this chunk

    for (int i = start; i < end; ++i) {
        int v = cnt[i];
        offs[i] = run;
        cursor[i] = run;
        run += v;
    }
    // thread whose chunk contains N-1 writes the total
    if (start < N && end == N) offs[N] = run;
}

__global__ __launch_bounds__(256) void scatter_kernel(const void* __restrict__ ep,
                                                      const int* __restrict__ flag,
                                                      int* __restrict__ cursor,
                                                      int* __restrict__ cols, int E) {
    int is64 = (*flag == 0);
    int e = blockIdx.x * blockDim.x + threadIdx.x;
    if (e < E) {
        int r = eload(ep, e, is64);
        int c = eload(ep, (long long)E + e, is64);
        int p = atomicAdd(&cursor[r], 1);
        cols[p] = c;
    }
}

// ---------------------------------------------------------------------------
__device__ __forceinline__ float4 unpack_bf16x4(uint2 v) {
    float4 r;
    r.x = __uint_as_float(v.x << 16);
    r.y = __uint_as_float(v.x & 0xffff0000u);
    r.z = __uint_as_float(v.y << 16);
    r.w = __uint_as_float(v.y & 0xffff0000u);
    return r;
}

// One wave per destination node; lane l owns dims 4l..4l+3 (uint2 = 4 bf16).
__global__ __launch_bounds__(256) void agg_bf16_kernel(const uint2* __restrict__ xb,
                                                       const float* __restrict__ s,
                                                       const int* __restrict__ offs,
                                                       const int* __restrict__ cols,
                                                       float4* __restrict__ out4, int N) {
    int lane = threadIdx.x & 63;
    int node = blockIdx.x * 4 + (threadIdx.x >> 6);
    if (node >= N) return;
    int beg = offs[node], end = offs[node + 1];
    float4 acc = make_float4(0.f, 0.f, 0.f, 0.f);
    float den = 0.f;
    int k = beg;
    for (; k + 2 <= end; k += 2) {
        int c0 = cols[k], c1 = cols[k + 1];
        float s0 = s[c0], s1 = s[c1];
        uint2 v0 = xb[(size_t)c0 * 64 + lane];
        uint2 v1 = xb[(size_t)c1 * 64 + lane];
        float4 f0 = unpack_bf16x4(v0);
        float4 f1 = unpack_bf16x4(v1);
        acc.x = fmaf(f0.x, s0, fmaf(f1.x, s1, acc.x));
        acc.y = fmaf(f0.y, s0, fmaf(f1.y, s1, acc.y));
        acc.z = fmaf(f0.z, s0, fmaf(f1.z, s1, acc.z));
        acc.w = fmaf(f0.w, s0, fmaf(f1.w, s1, acc.w));
        den += s0 + s1;
    }
    if (k < end) {
        int c0 = cols[k];
        float s0 = s[c0];
        float4 f0 = unpack_bf16x4(xb[(size_t)c0 * 64 + lane]);
        acc.x = fmaf(f0.x, s0, acc.x);
        acc.y = fmaf(f0.y, s0, acc.y);
        acc.z = fmaf(f0.z, s0, acc.z);
        acc.w = fmaf(f0.w, s0, acc.w);
        den += s0;
    }
    float4 o = make_float4(0.f, 0.f, 0.f, 0.f);
    if (end > beg) {
        float inv = 1.f / den;
        o.x = acc.x * inv; o.y = acc.y * inv; o.z = acc.z * inv; o.w = acc.w * inv;
    }
    out4[(size_t)node * 64 + lane] = o;
}

// fp32 fallback (used only if workspace can't hold the bf16 copy of x)
__global__ __launch_bounds__(256) void agg_kernel(const float4* __restrict__ x4,
                                                  const float* __restrict__ s,
                                                  const int* __restrict__ offs,
                                                  const int* __restrict__ cols,
                                                  float4* __restrict__ out4, int N) {
    int lane = threadIdx.x & 63;
    int node = blockIdx.x * 4 + (threadIdx.x >> 6);
    if (node >= N) return;
    int beg = offs[node], end = offs[node + 1];
    float4 acc = make_float4(0.f, 0.f, 0.f, 0.f);
    float den = 0.f;
    for (int k = beg; k < end; ++k) {
        int c = cols[k];
        float sc = s[c];
        float4 xv = x4[(size_t)c * 64 + lane];
        acc.x = fmaf(xv.x, sc, acc.x);
        acc.y = fmaf(xv.y, sc, acc.y);
        acc.z = fmaf(xv.z, sc, acc.z);
        acc.w = fmaf(xv.w, sc, acc.w);
        den += sc;
    }
    float4 o = make_float4(0.f, 0.f, 0.f, 0.f);
    if (end > beg) {
        float inv = 1.f / den;
        o.x = acc.x * inv; o.y = acc.y * inv; o.z = acc.z * inv; o.w = acc.w * inv;
    }
    out4[(size_t)node * 64 + lane] = o;
}

// ---------------------------------------------------------------------------
extern "C" void kernel_launch(void* const* d_in, const int* in_sizes, int n_in,
                              void* d_out, int out_size, void* d_ws, size_t ws_size,
                              hipStream_t stream) {
    const float* x  = (const float*)d_in[0];
    const void*  ei = d_in[1];
    const float* W1 = (const float*)d_in[2];
    const float* b1 = (const float*)d_in[3];
    const float* W2 = (const float*)d_in[4];
    const float* b2 = (const float*)d_in[5];
    int N = in_sizes[0] / D;
    int E = in_sizes[1] / 2;

    char* ws = (char*)d_ws;
    size_t o0 = 0;                                        // flag (16 B slot)
    size_t o1 = 16;                                       // cnt    : N ints
    size_t o2 = (o1 + (size_t)N * 4 + 15) & ~15ull;       // offs   : N+1 ints
    size_t o3 = (o2 + (size_t)(N + 1) * 4 + 15) & ~15ull; // cursor : N ints
    size_t o4 = (o3 + (size_t)N * 4 + 15) & ~15ull;       // s      : N floats
    size_t o5 = (o4 + (size_t)N * 4 + 15) & ~15ull;       // cols   : E ints
    size_t o6 = (o5 + (size_t)E * 4 + 255) & ~255ull;     // xb     : N*D bf16
    size_t need_bf16 = o6 + (size_t)N * D * 2;

    int*   flag   = (int*)(ws + o0);
    int*   cnt    = (int*)(ws + o1);
    int*   offs   = (int*)(ws + o2);
    int*   cursor = (int*)(ws + o3);
    float* s      = (float*)(ws + o4);
    int*   cols   = (int*)(ws + o5);
    uint2* xb     = (uint2*)(ws + o6);

    bool use_bf16 = (ws_size >= need_bf16);

    // zero flag + histogram
    hipMemsetAsync(ws, 0, o1 + (size_t)N * 4, stream);

    detect_kernel<<<1, 256, 0, stream>>>((const int*)ei, flag, E);
    if (use_bf16) {
        int n4 = N * (D / 4);
        cast_kernel<<<(n4 + 255) / 256, 256, 0, stream>>>((const uint4*)x, xb, n4);
    }
    score_kernel<<<(N + 4 * NB - 1) / (4 * NB), 256, 0, stream>>>(x, W1, b1, W2, b2, s, N);
    hist_kernel<<<(E + 255) / 256, 256, 0, stream>>>(ei, flag, cnt, E);
    scan_kernel<<<1, 1024, 0, stream>>>(cnt, offs, cursor, N);
    scatter_kernel<<<(E + 255) / 256, 256, 0, stream>>>(ei, flag, cursor, cols, E);
    if (use_bf16) {
        agg_bf16_kernel<<<(N + 3) / 4, 256, 0, stream>>>(xb, s, offs, cols,
                                                         (float4*)d_out, N);
    } else {
        agg_kernel<<<(N + 3) / 4, 256, 0, stream>>>((const float4*)x, s, offs, cols,
                                                    (float4*)d_out, N);
    }
}

// Round 3
// 338.447 us; speedup vs baseline: 1.3789x; 1.2601x over previous
//
#include <hip/hip_runtime.h>
#include <hip/hip_bf16.h>

#define D 256
#define DH 128
#define NB 8   // nodes per wave in score kernel

// ---------------------------------------------------------------------------
// Detect whether edge_index is int64 (high words all zero) or int32.
// flag must be pre-zeroed. After this kernel: flag==0 -> int64, else int32.
__global__ __launch_bounds__(256) void detect_kernel(const int* __restrict__ ei,
                                                     int* __restrict__ flag, int E) {
    int tid = threadIdx.x;
    int limit = min(E, 4096);
    int v = 0;
    for (int i = tid; i < limit; i += 256) v |= ei[2 * i + 1];
#pragma unroll
    for (int off = 32; off > 0; off >>= 1) v |= __shfl_down(v, off, 64);
    if ((tid & 63) == 0) atomicOr(flag, v);
}

__device__ __forceinline__ int eload(const void* p, long long i, int is64) {
    if (is64) return (int)((const long long*)p)[i];
    return ((const int*)p)[i];
}

// ---------------------------------------------------------------------------
// x (fp32) -> bf16 with round-to-nearest-even. n4 = count of float4 elements.
__device__ __forceinline__ unsigned pack_bf16(unsigned a, unsigned b) {
    unsigned ra = (a + 0x7fffu + ((a >> 16) & 1u)) >> 16;
    unsigned rb = (b + 0x7fffu + ((b >> 16) & 1u)) & 0xffff0000u;
    return ra | rb;
}

__global__ __launch_bounds__(256) void cast_kernel(const uint4* __restrict__ xi,
                                                   uint2* __restrict__ xb, int n4) {
    int i = blockIdx.x * blockDim.x + threadIdx.x;
    if (i < n4) {
        uint4 f = xi[i];
        uint2 o;
        o.x = pack_bf16(f.x, f.y);
        o.y = pack_bf16(f.z, f.w);
        xb[i] = o;
    }
}

// ---------------------------------------------------------------------------
// Per-node attention score: s[n] = sigmoid( relu(x[n]@W1 + b1) @ W2 + b2 )
// One wave handles NB=8 nodes; lane j computes hidden cols j and j+64.
__global__ __launch_bounds__(256) void score_kernel(const float* __restrict__ x,
                                                    const float* __restrict__ W1,
                                                    const float* __restrict__ b1,
                                                    const float* __restrict__ W2,
                                                    const float* __restrict__ b2,
                                                    float* __restrict__ s, int N) {
    __shared__ __align__(16) float xs[4][NB][D];   // 32 KB
    int lane = threadIdx.x & 63;
    int wid  = threadIdx.x >> 6;
    int base = (blockIdx.x * 4 + wid) * NB;

#pragma unroll
    for (int m = 0; m < NB; ++m) {
        int n = base + m;
        float4 v = make_float4(0.f, 0.f, 0.f, 0.f);
        if (n < N) v = ((const float4*)x)[(size_t)n * 64 + lane];
        ((float4*)&xs[wid][m][0])[lane] = v;
    }
    __syncthreads();

    float h0[NB], h1[NB];
#pragma unroll
    for (int m = 0; m < NB; ++m) { h0[m] = 0.f; h1[m] = 0.f; }

#pragma unroll 4
    for (int k = 0; k < D; ++k) {
        float w1a = W1[k * DH + lane];
        float w1b = W1[k * DH + 64 + lane];
#pragma unroll
        for (int m = 0; m < NB; ++m) {
            float xv = xs[wid][m][k];
            h0[m] = fmaf(xv, w1a, h0[m]);
            h1[m] = fmaf(xv, w1b, h1[m]);
        }
    }

    float b1a = b1[lane], b1b = b1[lane + 64];
    float w2a = W2[lane], w2b = W2[lane + 64];
    float b2v = b2[0];
#pragma unroll
    for (int m = 0; m < NB; ++m) {
        float za = fmaxf(h0[m] + b1a, 0.f) * w2a + fmaxf(h1[m] + b1b, 0.f) * w2b;
#pragma unroll
        for (int off = 32; off > 0; off >>= 1) za += __shfl_down(za, off, 64);
        if (lane == 0) {
            int n = base + m;
            if (n < N) s[n] = 1.f / (1.f + __expf(-(za + b2v)));
        }
    }
}

// ---------------------------------------------------------------------------
__global__ __launch_bounds__(256) void hist_kernel(const void* __restrict__ ep,
                                                   const int* __restrict__ flag,
                                                   int* __restrict__ cnt, int E) {
    int is64 = (*flag == 0);
    int e = blockIdx.x * blockDim.x + threadIdx.x;
    if (e < E) atomicAdd(&cnt[eload(ep, e, is64)], 1);
}

// ---------------------------------------------------------------------------
// Bucket allocator: each node gets a contiguous region of size cnt[n]; region
// order is arbitrary (wave-scan + one atomicAdd on a global cursor per wave).
// CSR does not require node-ordered buckets — agg uses beg[n] .. beg[n]+cnt[n].
__global__ __launch_bounds__(256) void bucket_kernel(const int* __restrict__ cnt,
                                                     int* __restrict__ beg,
                                                     int* __restrict__ cursor,
                                                     int* __restrict__ total, int N) {
    int i = blockIdx.x * blockDim.x + threadIdx.x;
    int lane = threadIdx.x & 63;
    int v = (i < N) ? cnt[i] : 0;
    int inc = v;
#pragma unroll
    for (int off = 1; off < 64; off <<= 1) {
        int t = __shfl_up(inc, off, 64);
        if (lane >= off) inc += t;
    }
    int base = 0;
    if (lane == 63) base = atomicAdd(total, inc);   // inc == wave sum at lane 63
    base = __shfl(base, 63, 64);
    if (i < N) {
        int b = base + inc - v;
        beg[i] = b;
        cursor[i] = b;
    }
}

__global__ __launch_bounds__(256) void scatter_kernel(const void* __restrict__ ep,
                                                      const int* __restrict__ flag,
                                                      int* __restrict__ cursor,
                                                      int* __restrict__ cols, int E) {
    int is64 = (*flag == 0);
    int e = blockIdx.x * blockDim.x + threadIdx.x;
    if (e < E) {
        int r = eload(ep, e, is64);
        int c = eload(ep, (long long)E + e, is64);
        int p = atomicAdd(&cursor[r], 1);
        cols[p] = c;
    }
}

// ---------------------------------------------------------------------------
__device__ __forceinline__ float4 unpack_bf16x4(uint2 v) {
    float4 r;
    r.x = __uint_as_float(v.x << 16);
    r.y = __uint_as_float(v.x & 0xffff0000u);
    r.z = __uint_as_float(v.y << 16);
    r.w = __uint_as_float(v.y & 0xffff0000u);
    return r;
}

// One wave per destination node; lane l owns dims 4l..4l+3 (uint2 = 4 bf16).
__global__ __launch_bounds__(256) void agg_bf16_kernel(const uint2* __restrict__ xb,
                                                       const float* __restrict__ s,
                                                       const int* __restrict__ begs,
                                                       const int* __restrict__ cnt,
                                                       const int* __restrict__ cols,
                                                       float4* __restrict__ out4, int N) {
    int lane = threadIdx.x & 63;
    int node = blockIdx.x * 4 + (threadIdx.x >> 6);
    if (node >= N) return;
    int beg = begs[node], end = beg + cnt[node];
    float4 acc = make_float4(0.f, 0.f, 0.f, 0.f);
    float den = 0.f;
    int k = beg;
    for (; k + 2 <= end; k += 2) {
        int c0 = cols[k], c1 = cols[k + 1];
        float s0 = s[c0], s1 = s[c1];
        uint2 v0 = xb[(size_t)c0 * 64 + lane];
        uint2 v1 = xb[(size_t)c1 * 64 + lane];
        float4 f0 = unpack_bf16x4(v0);
        float4 f1 = unpack_bf16x4(v1);
        acc.x = fmaf(f0.x, s0, fmaf(f1.x, s1, acc.x));
        acc.y = fmaf(f0.y, s0, fmaf(f1.y, s1, acc.y));
        acc.z = fmaf(f0.z, s0, fmaf(f1.z, s1, acc.z));
        acc.w = fmaf(f0.w, s0, fmaf(f1.w, s1, acc.w));
        den += s0 + s1;
    }
    if (k < end) {
        int c0 = cols[k];
        float s0 = s[c0];
        float4 f0 = unpack_bf16x4(xb[(size_t)c0 * 64 + lane]);
        acc.x = fmaf(f0.x, s0, acc.x);
        acc.y = fmaf(f0.y, s0, acc.y);
        acc.z = fmaf(f0.z, s0, acc.z);
        acc.w = fmaf(f0.w, s0, acc.w);
        den += s0;
    }
    float4 o = make_float4(0.f, 0.f, 0.f, 0.f);
    if (end > beg) {
        float inv = 1.f / den;
        o.x = acc.x * inv; o.y = acc.y * inv; o.z = acc.z * inv; o.w = acc.w * inv;
    }
    out4[(size_t)node * 64 + lane] = o;
}

// fp32 fallback (used only if workspace can't hold the bf16 copy of x)
__global__ __launch_bounds__(256) void agg_kernel(const float4* __restrict__ x4,
                                                  const float* __restrict__ s,
                                                  const int* __restrict__ begs,
                                                  const int* __restrict__ cnt,
                                                  const int* __restrict__ cols,
                                                  float4* __restrict__ out4, int N) {
    int lane = threadIdx.x & 63;
    int node = blockIdx.x * 4 + (threadIdx.x >> 6);
    if (node >= N) return;
    int beg = begs[node], end = beg + cnt[node];
    float4 acc = make_float4(0.f, 0.f, 0.f, 0.f);
    float den = 0.f;
    for (int k = beg; k < end; ++k) {
        int c = cols[k];
        float sc = s[c];
        float4 xv = x4[(size_t)c * 64 + lane];
        acc.x = fmaf(xv.x, sc, acc.x);
        acc.y = fmaf(xv.y, sc, acc.y);
        acc.z = fmaf(xv.z, sc, acc.z);
        acc.w = fmaf(xv.w, sc, acc.w);
        den += sc;
    }
    float4 o = make_float4(0.f, 0.f, 0.f, 0.f);
    if (end > beg) {
        float inv = 1.f / den;
        o.x = acc.x * inv; o.y = acc.y * inv; o.z = acc.z * inv; o.w = acc.w * inv;
    }
    out4[(size_t)node * 64 + lane] = o;
}

// ---------------------------------------------------------------------------
extern "C" void kernel_launch(void* const* d_in, const int* in_sizes, int n_in,
                              void* d_out, int out_size, void* d_ws, size_t ws_size,
                              hipStream_t stream) {
    const float* x  = (const float*)d_in[0];
    const void*  ei = d_in[1];
    const float* W1 = (const float*)d_in[2];
    const float* b1 = (const float*)d_in[3];
    const float* W2 = (const float*)d_in[4];
    const float* b2 = (const float*)d_in[5];
    int N = in_sizes[0] / D;
    int E = in_sizes[1] / 2;

    char* ws = (char*)d_ws;
    size_t o0 = 0;                                        // flag @0, total @4 (16 B slot)
    size_t o1 = 16;                                       // cnt    : N ints
    size_t o2 = (o1 + (size_t)N * 4 + 15) & ~15ull;       // beg    : N ints
    size_t o3 = (o2 + (size_t)N * 4 + 15) & ~15ull;       // cursor : N ints
    size_t o4 = (o3 + (size_t)N * 4 + 15) & ~15ull;       // s      : N floats
    size_t o5 = (o4 + (size_t)N * 4 + 15) & ~15ull;       // cols   : E ints
    size_t o6 = (o5 + (size_t)E * 4 + 255) & ~255ull;     // xb     : N*D bf16
    size_t need_bf16 = o6 + (size_t)N * D * 2;

    int*   flag   = (int*)(ws + o0);
    int*   total  = (int*)(ws + o0 + 4);
    int*   cnt    = (int*)(ws + o1);
    int*   beg    = (int*)(ws + o2);
    int*   cursor = (int*)(ws + o3);
    float* s      = (float*)(ws + o4);
    int*   cols   = (int*)(ws + o5);
    uint2* xb     = (uint2*)(ws + o6);

    bool use_bf16 = (ws_size >= need_bf16);

    // zero flag + total + histogram counters
    hipMemsetAsync(ws, 0, o1 + (size_t)N * 4, stream);

    detect_kernel<<<1, 256, 0, stream>>>((const int*)ei, flag, E);
    if (use_bf16) {
        int n4 = N * (D / 4);
        cast_kernel<<<(n4 + 255) / 256, 256, 0, stream>>>((const uint4*)x, xb, n4);
    }
    score_kernel<<<(N + 4 * NB - 1) / (4 * NB), 256, 0, stream>>>(x, W1, b1, W2, b2, s, N);
    hist_kernel<<<(E + 255) / 256, 256, 0, stream>>>(ei, flag, cnt, E);
    bucket_kernel<<<(N + 255) / 256, 256, 0, stream>>>(cnt, beg, cursor, total, N);
    scatter_kernel<<<(E + 255) / 256, 256, 0, stream>>>(ei, flag, cursor, cols, E);
    if (use_bf16) {
        agg_bf16_kernel<<<(N + 3) / 4, 256, 0, stream>>>(xb, s, beg, cnt, cols,
                                                         (float4*)d_out, N);
    } else {
        agg_kernel<<<(N + 3) / 4, 256, 0, stream>>>((const float4*)x, s, beg, cnt, cols,
                                                    (float4*)d_out, N);
    }
}

// Round 4
// 291.328 us; speedup vs baseline: 1.6019x; 1.1617x over previous
//
#include <hip/hip_runtime.h>
#include <hip/hip_bf16.h>

#define D 256
#define DH 128
#define NB 8   // nodes per wave in fallback score kernel

typedef __attribute__((ext_vector_type(8))) short short8;
typedef __attribute__((ext_vector_type(4))) float floatx4;

// ---------------------------------------------------------------------------
// Detect whether edge_index is int64 (high words all zero) or int32.
__global__ __launch_bounds__(256) void detect_kernel(const int* __restrict__ ei,
                                                     int* __restrict__ flag, int E) {
    int tid = threadIdx.x;
    int limit = min(E, 4096);
    int v = 0;
    for (int i = tid; i < limit; i += 256) v |= ei[2 * i + 1];
#pragma unroll
    for (int off = 32; off > 0; off >>= 1) v |= __shfl_down(v, off, 64);
    if ((tid & 63) == 0) atomicOr(flag, v);
}

__device__ __forceinline__ int eload(const void* p, long long i, int is64) {
    if (is64) return (int)((const long long*)p)[i];
    return ((const int*)p)[i];
}

// fp32 bits -> bf16 (RNE), packed pair
__device__ __forceinline__ unsigned pack_bf16(unsigned a, unsigned b) {
    unsigned ra = (a + 0x7fffu + ((a >> 16) & 1u)) >> 16;
    unsigned rb = (b + 0x7fffu + ((b >> 16) & 1u)) & 0xffff0000u;
    return ra | rb;
}
__device__ __forceinline__ unsigned short bf16_of(float f) {
    unsigned u = __float_as_uint(f);
    return (unsigned short)((u + 0x7fffu + ((u >> 16) & 1u)) >> 16);
}

// ---------------------------------------------------------------------------
// Pre-pack W1 (fp32 [256][128]) into bf16 B-fragment order for 16x16x32 MFMA:
// fragment (nt,kt), lane l holds B[k=kt*32+(l>>4)*8+j][n=nt*16+(l&15)], j=0..7.
// One thread per (nt,kt,lane): 4096 threads.
__global__ __launch_bounds__(256) void pack_w1_kernel(const float* __restrict__ W1,
                                                      uint4* __restrict__ Bp) {
    int t = blockIdx.x * 256 + threadIdx.x;     // 0..4095
    int lane = t & 63;
    int kt = (t >> 6) & 7;
    int nt = t >> 9;
    int col = nt * 16 + (lane & 15);
    int k0 = kt * 32 + (lane >> 4) * 8;
    unsigned v[8];
#pragma unroll
    for (int j = 0; j < 8; ++j) v[j] = __float_as_uint(W1[(k0 + j) * DH + col]);
    uint4 o;
    o.x = pack_bf16(v[0], v[1]);
    o.y = pack_bf16(v[2], v[3]);
    o.z = pack_bf16(v[4], v[5]);
    o.w = pack_bf16(v[6], v[7]);
    Bp[t] = o;
}

// ---------------------------------------------------------------------------
// Fused: (a) cast x -> xb (bf16, coalesced), (b) per-node score via MFMA:
// s[n] = sigmoid(relu(x@W1+b1)@W2+b2). Block = 4 waves, 64 rows; wave w
// computes rows [blk*64+w*16, +16) x all 128 hidden cols as 8 n-tiles.
__global__ __launch_bounds__(256) void score_mfma_kernel(const float* __restrict__ x,
                                                         const uint4* __restrict__ Bp,
                                                         const float* __restrict__ b1,
                                                         const float* __restrict__ W2,
                                                         const float* __restrict__ b2,
                                                         uint2* __restrict__ xb,
                                                         float* __restrict__ s, int N) {
    int tid = threadIdx.x;
    long long n64 = (long long)N * 64;

    // ---- phase A: coalesced cast of this block's 64 rows (4096 float4s)
    long long gbase = (long long)blockIdx.x * 4096 + tid;
#pragma unroll 4
    for (int i = 0; i < 16; ++i) {
        long long g = gbase + i * 256;
        if (g < n64) {
            uint4 f = ((const uint4*)x)[g];
            uint2 o;
            o.x = pack_bf16(f.x, f.y);
            o.y = pack_bf16(f.z, f.w);
            xb[g] = o;
        }
    }

    // ---- phase B: MFMA score for this wave's 16 rows
    int lane = tid & 63;
    int wid = tid >> 6;
    int quad = lane >> 4;
    int rbase = blockIdx.x * 64 + wid * 16;

    int arow = rbase + (lane & 15);
    bool rv = arow < N;
    const float* xr = x + (size_t)(rv ? arow : 0) * D + quad * 8;

    short8 afrag[8];
#pragma unroll
    for (int kt = 0; kt < 8; ++kt) {
        float4 f0 = make_float4(0.f, 0.f, 0.f, 0.f), f1 = f0;
        if (rv) {
            f0 = ((const float4*)(xr + kt * 32))[0];
            f1 = ((const float4*)(xr + kt * 32))[1];
        }
        short8 a;
        a.s0 = (short)bf16_of(f0.x); a.s1 = (short)bf16_of(f0.y);
        a.s2 = (short)bf16_of(f0.z); a.s3 = (short)bf16_of(f0.w);
        a.s4 = (short)bf16_of(f1.x); a.s5 = (short)bf16_of(f1.y);
        a.s6 = (short)bf16_of(f1.z); a.s7 = (short)bf16_of(f1.w);
        afrag[kt] = a;
    }

    float z0 = 0.f, z1 = 0.f, z2 = 0.f, z3 = 0.f;
#pragma unroll
    for (int nt = 0; nt < 8; ++nt) {
        floatx4 acc = {0.f, 0.f, 0.f, 0.f};
#pragma unroll
        for (int kt = 0; kt < 8; ++kt) {
            uint4 braw = Bp[(nt * 8 + kt) * 64 + lane];
            short8 b;
            b.s0 = (short)(braw.x & 0xffff); b.s1 = (short)(braw.x >> 16);
            b.s2 = (short)(braw.y & 0xffff); b.s3 = (short)(braw.y >> 16);
            b.s4 = (short)(braw.z & 0xffff); b.s5 = (short)(braw.z >> 16);
            b.s6 = (short)(braw.w & 0xffff); b.s7 = (short)(braw.w >> 16);
            acc = __builtin_amdgcn_mfma_f32_16x16x32_bf16(afrag[kt], b, acc, 0, 0, 0);
        }
        int col = nt * 16 + (lane & 15);
        float b1c = b1[col], w2c = W2[col];
        z0 += fmaxf(acc[0] + b1c, 0.f) * w2c;
        z1 += fmaxf(acc[1] + b1c, 0.f) * w2c;
        z2 += fmaxf(acc[2] + b1c, 0.f) * w2c;
        z3 += fmaxf(acc[3] + b1c, 0.f) * w2c;
    }

    // reduce across the 16 lanes of each quad-group (cols of the C tile)
#pragma unroll
    for (int off = 1; off < 16; off <<= 1) {
        z0 += __shfl_xor(z0, off, 64);
        z1 += __shfl_xor(z1, off, 64);
        z2 += __shfl_xor(z2, off, 64);
        z3 += __shfl_xor(z3, off, 64);
    }
    if ((lane & 15) == 0) {
        float b2v = b2[0];
        int r = rbase + quad * 4;
        float zz[4] = {z0, z1, z2, z3};
#pragma unroll
        for (int j = 0; j < 4; ++j)
            if (r + j < N) s[r + j] = 1.f / (1.f + __expf(-(zz[j] + b2v)));
    }
}

// ---------------------------------------------------------------------------
// Fallback fp32 score kernel (used only if workspace too small for MFMA path)
__global__ __launch_bounds__(256) void score_kernel(const float* __restrict__ x,
                                                    const float* __restrict__ W1,
                                                    const float* __restrict__ b1,
                                                    const float* __restrict__ W2,
                                                    const float* __restrict__ b2,
                                                    float* __restrict__ s, int N) {
    __shared__ __align__(16) float xs[4][NB][D];
    int lane = threadIdx.x & 63;
    int wid  = threadIdx.x >> 6;
    int base = (blockIdx.x * 4 + wid) * NB;
#pragma unroll
    for (int m = 0; m < NB; ++m) {
        int n = base + m;
        float4 v = make_float4(0.f, 0.f, 0.f, 0.f);
        if (n < N) v = ((const float4*)x)[(size_t)n * 64 + lane];
        ((float4*)&xs[wid][m][0])[lane] = v;
    }
    __syncthreads();
    float h0[NB], h1[NB];
#pragma unroll
    for (int m = 0; m < NB; ++m) { h0[m] = 0.f; h1[m] = 0.f; }
#pragma unroll 4
    for (int k = 0; k < D; ++k) {
        float w1a = W1[k * DH + lane];
        float w1b = W1[k * DH + 64 + lane];
#pragma unroll
        for (int m = 0; m < NB; ++m) {
            float xv = xs[wid][m][k];
            h0[m] = fmaf(xv, w1a, h0[m]);
            h1[m] = fmaf(xv, w1b, h1[m]);
        }
    }
    float b1a = b1[lane], b1b = b1[lane + 64];
    float w2a = W2[lane], w2b = W2[lane + 64];
    float b2v = b2[0];
#pragma unroll
    for (int m = 0; m < NB; ++m) {
        float za = fmaxf(h0[m] + b1a, 0.f) * w2a + fmaxf(h1[m] + b1b, 0.f) * w2b;
#pragma unroll
        for (int off = 32; off > 0; off >>= 1) za += __shfl_down(za, off, 64);
        if (lane == 0) {
            int n = base + m;
            if (n < N) s[n] = 1.f / (1.f + __expf(-(za + b2v)));
        }
    }
}

// ---------------------------------------------------------------------------
__global__ __launch_bounds__(256) void hist_kernel(const void* __restrict__ ep,
                                                   const int* __restrict__ flag,
                                                   int* __restrict__ cnt, int E) {
    int is64 = (*flag == 0);
    int e = blockIdx.x * blockDim.x + threadIdx.x;
    if (e < E) atomicAdd(&cnt[eload(ep, e, is64)], 1);
}

// Bucket allocator: contiguous region per node, arbitrary order.
__global__ __launch_bounds__(256) void bucket_kernel(const int* __restrict__ cnt,
                                                     int* __restrict__ beg,
                                                     int* __restrict__ cursor,
                                                     int* __restrict__ total, int N) {
    int i = blockIdx.x * blockDim.x + threadIdx.x;
    int lane = threadIdx.x & 63;
    int v = (i < N) ? cnt[i] : 0;
    int inc = v;
#pragma unroll
    for (int off = 1; off < 64; off <<= 1) {
        int t = __shfl_up(inc, off, 64);
        if (lane >= off) inc += t;
    }
    int base = 0;
    if (lane == 63) base = atomicAdd(total, inc);
    base = __shfl(base, 63, 64);
    if (i < N) {
        int b = base + inc - v;
        beg[i] = b;
        cursor[i] = b;
    }
}

__global__ __launch_bounds__(256) void scatter_kernel(const void* __restrict__ ep,
                                                      const int* __restrict__ flag,
                                                      int* __restrict__ cursor,
                                                      int* __restrict__ cols, int E) {
    int is64 = (*flag == 0);
    int e = blockIdx.x * blockDim.x + threadIdx.x;
    if (e < E) {
        int r = eload(ep, e, is64);
        int c = eload(ep, (long long)E + e, is64);
        int p = atomicAdd(&cursor[r], 1);
        cols[p] = c;
    }
}

// ---------------------------------------------------------------------------
__device__ __forceinline__ float4 unpack_bf16x4(uint2 v) {
    float4 r;
    r.x = __uint_as_float(v.x << 16);
    r.y = __uint_as_float(v.x & 0xffff0000u);
    r.z = __uint_as_float(v.y << 16);
    r.w = __uint_as_float(v.y & 0xffff0000u);
    return r;
}

// One wave per destination node; lane l owns dims 4l..4l+3 (uint2 = 4 bf16).
__global__ __launch_bounds__(256) void agg_bf16_kernel(const uint2* __restrict__ xb,
                                                       const float* __restrict__ s,
                                                       const int* __restrict__ begs,
                                                       const int* __restrict__ cnt,
                                                       const int* __restrict__ cols,
                                                       float4* __restrict__ out4, int N) {
    int lane = threadIdx.x & 63;
    int node = blockIdx.x * 4 + (threadIdx.x >> 6);
    if (node >= N) return;
    int beg = begs[node], end = beg + cnt[node];
    float4 acc = make_float4(0.f, 0.f, 0.f, 0.f);
    float den = 0.f;
    int k = beg;
    for (; k + 2 <= end; k += 2) {
        int c0 = cols[k], c1 = cols[k + 1];
        float s0 = s[c0], s1 = s[c1];
        uint2 v0 = xb[(size_t)c0 * 64 + lane];
        uint2 v1 = xb[(size_t)c1 * 64 + lane];
        float4 f0 = unpack_bf16x4(v0);
        float4 f1 = unpack_bf16x4(v1);
        acc.x = fmaf(f0.x, s0, fmaf(f1.x, s1, acc.x));
        acc.y = fmaf(f0.y, s0, fmaf(f1.y, s1, acc.y));
        acc.z = fmaf(f0.z, s0, fmaf(f1.z, s1, acc.z));
        acc.w = fmaf(f0.w, s0, fmaf(f1.w, s1, acc.w));
        den += s0 + s1;
    }
    if (k < end) {
        int c0 = cols[k];
        float s0 = s[c0];
        float4 f0 = unpack_bf16x4(xb[(size_t)c0 * 64 + lane]);
        acc.x = fmaf(f0.x, s0, acc.x);
        acc.y = fmaf(f0.y, s0, acc.y);
        acc.z = fmaf(f0.z, s0, acc.z);
        acc.w = fmaf(f0.w, s0, acc.w);
        den += s0;
    }
    float4 o = make_float4(0.f, 0.f, 0.f, 0.f);
    if (end > beg) {
        float inv = 1.f / den;
        o.x = acc.x * inv; o.y = acc.y * inv; o.z = acc.z * inv; o.w = acc.w * inv;
    }
    out4[(size_t)node * 64 + lane] = o;
}

// fp32 fallback aggregation
__global__ __launch_bounds__(256) void agg_kernel(const float4* __restrict__ x4,
                                                  const float* __restrict__ s,
                                                  const int* __restrict__ begs,
                                                  const int* __restrict__ cnt,
                                                  const int* __restrict__ cols,
                                                  float4* __restrict__ out4, int N) {
    int lane = threadIdx.x & 63;
    int node = blockIdx.x * 4 + (threadIdx.x >> 6);
    if (node >= N) return;
    int beg = begs[node], end = beg + cnt[node];
    float4 acc = make_float4(0.f, 0.f, 0.f, 0.f);
    float den = 0.f;
    for (int k = beg; k < end; ++k) {
        int c = cols[k];
        float sc = s[c];
        float4 xv = x4[(size_t)c * 64 + lane];
        acc.x = fmaf(xv.x, sc, acc.x);
        acc.y = fmaf(xv.y, sc, acc.y);
        acc.z = fmaf(xv.z, sc, acc.z);
        acc.w = fmaf(xv.w, sc, acc.w);
        den += sc;
    }
    float4 o = make_float4(0.f, 0.f, 0.f, 0.f);
    if (end > beg) {
        float inv = 1.f / den;
        o.x = acc.x * inv; o.y = acc.y * inv; o.z = acc.z * inv; o.w = acc.w * inv;
    }
    out4[(size_t)node * 64 + lane] = o;
}

// ---------------------------------------------------------------------------
extern "C" void kernel_launch(void* const* d_in, const int* in_sizes, int n_in,
                              void* d_out, int out_size, void* d_ws, size_t ws_size,
                              hipStream_t stream) {
    const float* x  = (const float*)d_in[0];
    const void*  ei = d_in[1];
    const float* W1 = (const float*)d_in[2];
    const float* b1 = (const float*)d_in[3];
    const float* W2 = (const float*)d_in[4];
    const float* b2 = (const float*)d_in[5];
    int N = in_sizes[0] / D;
    int E = in_sizes[1] / 2;

    char* ws = (char*)d_ws;
    size_t o0 = 0;                                        // flag @0, total @4
    size_t o1 = 16;                                       // cnt    : N ints
    size_t o2 = (o1 + (size_t)N * 4 + 15) & ~15ull;       // beg    : N ints
    size_t o3 = (o2 + (size_t)N * 4 + 15) & ~15ull;       // cursor : N ints
    size_t o4 = (o3 + (size_t)N * 4 + 15) & ~15ull;       // s      : N floats
    size_t o5 = (o4 + (size_t)N * 4 + 15) & ~15ull;       // cols   : E ints
    size_t o6 = (o5 + (size_t)E * 4 + 255) & ~255ull;     // Bpack  : 64 KB
    size_t o7 = (o6 + 65536 + 255) & ~255ull;             // xb     : N*D bf16
    size_t need_bf16 = o7 + (size_t)N * D * 2;

    int*   flag   = (int*)(ws + o0);
    int*   total  = (int*)(ws + o0 + 4);
    int*   cnt    = (int*)(ws + o1);
    int*   beg    = (int*)(ws + o2);
    int*   cursor = (int*)(ws + o3);
    float* s      = (float*)(ws + o4);
    int*   cols   = (int*)(ws + o5);
    uint4* Bpack  = (uint4*)(ws + o6);
    uint2* xb     = (uint2*)(ws + o7);

    bool use_bf16 = (ws_size >= need_bf16);

    // zero flag + total + histogram counters
    hipMemsetAsync(ws, 0, o1 + (size_t)N * 4, stream);

    detect_kernel<<<1, 256, 0, stream>>>((const int*)ei, flag, E);
    if (use_bf16) {
        pack_w1_kernel<<<16, 256, 0, stream>>>(W1, Bpack);
        score_mfma_kernel<<<(N + 63) / 64, 256, 0, stream>>>(x, Bpack, b1, W2, b2,
                                                             xb, s, N);
    } else {
        score_kernel<<<(N + 4 * NB - 1) / (4 * NB), 256, 0, stream>>>(x, W1, b1, W2,
                                                                      b2, s, N);
    }
    hist_kernel<<<(E + 255) / 256, 256, 0, stream>>>(ei, flag, cnt, E);
    bucket_kernel<<<(N + 255) / 256, 256, 0, stream>>>(cnt, beg, cursor, total, N);
    scatter_kernel<<<(E + 255) / 256, 256, 0, stream>>>(ei, flag, cursor, cols, E);
    if (use_bf16) {
        agg_bf16_kernel<<<(N + 3) / 4, 256, 0, stream>>>(xb, s, beg, cnt, cols,
                                                         (float4*)d_out, N);
    } else {
        agg_kernel<<<(N + 3) / 4, 256, 0, stream>>>((const float4*)x, s, beg, cnt, cols,
                                                    (float4*)d_out, N);
    }
}